// Round 1
// baseline (226.865 us; speedup 1.0000x reference)
//
#include <hip/hip_runtime.h>
#include <hip/hip_bf16.h>

// Florence2VisionWindowAttention on MI355X (gfx950), bf16-MFMA pipeline.
// Workspace layout (u16 elements), total ~92 MB:
//   xw      : 18432*512    windowed x, bf16
//   qkvT    : 1536*512     qkv_w^T, bf16
//   projT   : 512*512      proj_w^T, bf16
//   qkvout  : 18432*1536   QKV activations, bf16 (window-ordered rows)
//   attno   : 18432*512    attention output, bf16 (window-ordered rows)

typedef unsigned short u16;
typedef unsigned int u32;
typedef __attribute__((ext_vector_type(4))) float f32x4;
typedef __attribute__((ext_vector_type(8))) short short8;

#define MFMA16(a, b, c) __builtin_amdgcn_mfma_f32_16x16x32_bf16(a, b, c, 0, 0, 0)

__device__ __forceinline__ u16 f2b(float f) {
  __hip_bfloat16 h = __float2bfloat16(f);
  return *reinterpret_cast<u16*>(&h);
}

// ---------------- prep: gather x into window order + fp32->bf16 ----------------
__global__ void prep_x_kernel(const float* __restrict__ x, u16* __restrict__ xw) {
  int c = blockIdx.x * 256 + threadIdx.x;   // one 8-element chunk
  int r = c >> 6;                           // row in [0,18432): win*144+tok
  int colb = (c & 63) << 3;
  int win = r / 144, tok = r - win * 144;
  int b = win >> 4, wh = (win >> 2) & 3, ww = win & 3;
  int i = tok / 12, j = tok - i * 12;
  const float* src = x + ((size_t)((b * 48 + wh * 12 + i) * 48 + ww * 12 + j)) * 512 + colb;
  float4 a0 = *(const float4*)(src);
  float4 a1 = *(const float4*)(src + 4);
  short8 o;
  o[0] = (short)f2b(a0.x); o[1] = (short)f2b(a0.y); o[2] = (short)f2b(a0.z); o[3] = (short)f2b(a0.w);
  o[4] = (short)f2b(a1.x); o[5] = (short)f2b(a1.y); o[6] = (short)f2b(a1.z); o[7] = (short)f2b(a1.w);
  *reinterpret_cast<short8*>(xw + (size_t)r * 512 + colb) = o;
}

// ---------------- prep: weight transpose K x N -> N x K bf16 ----------------
__global__ void prep_wt_kernel(const float* __restrict__ w, u16* __restrict__ wt,
                               int K, int N) {
  int t = blockIdx.x * 256 + threadIdx.x;
  int nchunks = N >> 3;
  if (t >= K * nchunks) return;
  int k = t / nchunks;
  int n0 = (t - k * nchunks) << 3;
  const float* src = w + (size_t)k * N + n0;   // coalesced read
  float4 a0 = *(const float4*)(src);
  float4 a1 = *(const float4*)(src + 4);
  float v[8] = {a0.x, a0.y, a0.z, a0.w, a1.x, a1.y, a1.z, a1.w};
#pragma unroll
  for (int j = 0; j < 8; j++) wt[(size_t)(n0 + j) * K + k] = f2b(v[j]);
}

// ---------------- GEMM: C = A(MxK) * BT(NxK)^T + bias ----------------
// EPI==0: bf16 output, row-major MxN.  EPI==1: fp32 output with window_reverse.
template <int EPI>
__global__ __launch_bounds__(256) void gemm_bt_kernel(
    const u16* __restrict__ A, const u16* __restrict__ BT,
    const float* __restrict__ bias,
    u16* __restrict__ outb, float* __restrict__ outf,
    int M, int N, int K) {
  __shared__ __align__(16) u16 sA[128 * 64];
  __shared__ __align__(16) u16 sB[128 * 64];
  const int tid = threadIdx.x;
  const int wave = tid >> 6;
  const int lane = tid & 63;
  const int bm = blockIdx.x;
  const int bn = blockIdx.y;
  const int wr = (wave >> 1) << 6;   // wave row offset in 128x128 tile
  const int wc = (wave & 1) << 6;    // wave col offset
  const int l15 = lane & 15;
  const int lhi = lane >> 4;

  f32x4 acc[4][4];
  const f32x4 fzero = {0.f, 0.f, 0.f, 0.f};
#pragma unroll
  for (int i = 0; i < 4; i++)
#pragma unroll
    for (int j = 0; j < 4; j++) acc[i][j] = fzero;

  const int srow = lane >> 3;          // 8 rows per 1024B chunk
  const int scol = (lane & 7) << 3;    // element offset in row
  const u16* Abase = A + (size_t)(bm * 128) * K;
  const u16* Bbase = BT + (size_t)(bn * 128) * K;

  for (int k0 = 0; k0 < K; k0 += 64) {
#pragma unroll
    for (int i = 0; i < 4; ++i) {
      const int chunk = wave * 4 + i;          // wave-uniform
      const int row = chunk * 8 + srow;
      __builtin_amdgcn_global_load_lds(
          (const __attribute__((address_space(1))) u32*)(Abase + (size_t)row * K + k0 + scol),
          (__attribute__((address_space(3))) u32*)(sA + chunk * 512), 16, 0, 0);
      __builtin_amdgcn_global_load_lds(
          (const __attribute__((address_space(1))) u32*)(Bbase + (size_t)row * K + k0 + scol),
          (__attribute__((address_space(3))) u32*)(sB + chunk * 512), 16, 0, 0);
    }
    __syncthreads();   // compiler drains vmcnt before barrier

    short8 af[4][2], bfr[4][2];
#pragma unroll
    for (int t = 0; t < 4; t++) {
#pragma unroll
      for (int kk = 0; kk < 2; kk++) {
        af[t][kk]  = *reinterpret_cast<const short8*>(sA + (wr + t * 16 + l15) * 64 + kk * 32 + lhi * 8);
        bfr[t][kk] = *reinterpret_cast<const short8*>(sB + (wc + t * 16 + l15) * 64 + kk * 32 + lhi * 8);
      }
    }
#pragma unroll
    for (int kk = 0; kk < 2; kk++)
#pragma unroll
      for (int i = 0; i < 4; i++)
#pragma unroll
        for (int j = 0; j < 4; j++)
          acc[i][j] = MFMA16(af[i][kk], bfr[j][kk], acc[i][j]);
    __syncthreads();
  }

#pragma unroll
  for (int i = 0; i < 4; i++) {
    const int rowbase = bm * 128 + wr + i * 16 + lhi * 4;
#pragma unroll
    for (int j = 0; j < 4; j++) {
      const int col = bn * 128 + wc + j * 16 + l15;
      const float bv = bias[col];
#pragma unroll
      for (int r = 0; r < 4; r++) {
        float v = acc[i][j][r] + bv;
        int row = rowbase + r;
        if (EPI == 0) {
          outb[(size_t)row * N + col] = f2b(v);
        } else {
          int win = row / 144, tok = row - win * 144;
          int b = win >> 4, wh = (win >> 2) & 3, ww = win & 3;
          int ii = tok / 12, jj = tok - ii * 12;
          size_t o = ((size_t)b * 2304 + (wh * 12 + ii) * 48 + (ww * 12 + jj)) * 512 + col;
          outf[o] = v;
        }
      }
    }
  }
}

// ---------------- fused window attention: one block per (window, head) ----------------
// 192 threads = 3 waves, each wave owns 48 q-rows. hd=32, 144 tokens.
__global__ __launch_bounds__(192) void attn_kernel(const u16* __restrict__ qkv,
                                                   u16* __restrict__ outb) {
  constexpr int PSTR = 168;                    // padded row stride (b128-aligned, bank-spread)
  __shared__ __align__(16) u16 sP[3 * 48 * PSTR];   // per-wave P (48 x 160 used)
  __shared__ __align__(16) u16 sVT[32 * PSTR];      // V^T (32 x 160 used)
  const int tid = threadIdx.x;
  const int wave = tid >> 6;
  const int lane = tid & 63;
  const int l15 = lane & 15;
  const int lhi = lane >> 4;
  const int win = blockIdx.x;
  const int head = blockIdx.y;
  const size_t base = ((size_t)win * 144) * 1536 + head * 32;
  const u16* Q = qkv + base;
  const u16* Kp = qkv + base + 512;
  const u16* V = qkv + base + 1024;
  constexpr float SCALE = 0.17677669529663687f;  // 1/sqrt(32)
  const f32x4 fzero = {0.f, 0.f, 0.f, 0.f};

  // stage V^T into LDS (transpose): VT[d][tok]
  for (int t = tid; t < 576; t += 192) {
    int tok = t >> 2, dblk = t & 3;
    short8 v = *reinterpret_cast<const short8*>(V + (size_t)tok * 1536 + dblk * 8);
#pragma unroll
    for (int j = 0; j < 8; j++) sVT[(dblk * 8 + j) * PSTR + tok] = (u16)v[j];
  }
  for (int t = tid; t < 512; t += 192) {       // zero pad tok 144..159
    int d = t >> 4, cc = 144 + (t & 15);
    sVT[d * PSTR + cc] = 0;
  }
  u16* sPw = sP + wave * 48 * PSTR;
  for (int t = lane; t < 768; t += 64) {       // zero own-wave P pad cols 144..159
    int rr = t >> 4, cc = 144 + (t & 15);
    sPw[rr * PSTR + cc] = 0;
  }

  // Q fragments (A-operand): row = q-token, 8 contiguous hd elems per lane
  short8 qa[3];
#pragma unroll
  for (int mt = 0; mt < 3; mt++) {
    int row = wave * 48 + mt * 16 + l15;
    qa[mt] = *reinterpret_cast<const short8*>(Q + (size_t)row * 1536 + lhi * 8);
  }

  // S = Q K^T : 3x9 tiles of 16x16, K=32 (one MFMA each)
  f32x4 s[3][9];
#pragma unroll
  for (int nt = 0; nt < 9; nt++) {
    int ctok = nt * 16 + l15;
    short8 kb = *reinterpret_cast<const short8*>(Kp + (size_t)ctok * 1536 + lhi * 8);
#pragma unroll
    for (int mt = 0; mt < 3; mt++) s[mt][nt] = MFMA16(qa[mt], kb, fzero);
  }

  // softmax per row (row = mt*16 + lhi*4 + r; cols spread over 16-lane group x 9 tiles)
#pragma unroll
  for (int mt = 0; mt < 3; mt++) {
#pragma unroll
    for (int r = 0; r < 4; r++) {
      float m = -1e30f;
#pragma unroll
      for (int nt = 0; nt < 9; nt++) m = fmaxf(m, s[mt][nt][r]);
#pragma unroll
      for (int off = 1; off < 16; off <<= 1) m = fmaxf(m, __shfl_xor(m, off, 64));
      float p[9], sum = 0.f;
#pragma unroll
      for (int nt = 0; nt < 9; nt++) {
        p[nt] = __expf((s[mt][nt][r] - m) * SCALE);
        sum += p[nt];
      }
#pragma unroll
      for (int off = 1; off < 16; off <<= 1) sum += __shfl_xor(sum, off, 64);
      float inv = 1.f / sum;
      int prow = mt * 16 + lhi * 4 + r;
#pragma unroll
      for (int nt = 0; nt < 9; nt++)
        sPw[prow * PSTR + nt * 16 + l15] = f2b(p[nt] * inv);
    }
  }

  __syncthreads();   // sVT complete for all waves

  // O = P V : 3x2 tiles, K padded to 160 (5 MFMA steps)
  f32x4 o[3][2];
#pragma unroll
  for (int mt = 0; mt < 3; mt++)
#pragma unroll
    for (int nt = 0; nt < 2; nt++) o[mt][nt] = fzero;
#pragma unroll
  for (int kk = 0; kk < 5; kk++) {
    short8 pa[3];
#pragma unroll
    for (int mt = 0; mt < 3; mt++)
      pa[mt] = *reinterpret_cast<const short8*>(sPw + (mt * 16 + l15) * PSTR + kk * 32 + lhi * 8);
#pragma unroll
    for (int nt = 0; nt < 2; nt++) {
      short8 vb = *reinterpret_cast<const short8*>(sVT + (nt * 16 + l15) * PSTR + kk * 32 + lhi * 8);
#pragma unroll
      for (int mt = 0; mt < 3; mt++) o[mt][nt] = MFMA16(pa[mt], vb, o[mt][nt]);
    }
  }

  // write O as bf16 into (M x 512) row-major (window-ordered rows)
  const int rowb = win * 144 + wave * 48;
#pragma unroll
  for (int mt = 0; mt < 3; mt++) {
#pragma unroll
    for (int nt = 0; nt < 2; nt++) {
      int col = head * 32 + nt * 16 + l15;
#pragma unroll
      for (int r = 0; r < 4; r++) {
        int row = rowb + mt * 16 + lhi * 4 + r;
        outb[(size_t)row * 512 + col] = f2b(o[mt][nt][r]);
      }
    }
  }
}

// ---------------- launch ----------------
extern "C" void kernel_launch(void* const* d_in, const int* in_sizes, int n_in,
                              void* d_out, int out_size, void* d_ws, size_t ws_size,
                              hipStream_t stream) {
  const float* x      = (const float*)d_in[0];
  const float* qkv_w  = (const float*)d_in[1];
  const float* qkv_b  = (const float*)d_in[2];
  const float* proj_w = (const float*)d_in[3];
  const float* proj_b = (const float*)d_in[4];
  float* out = (float*)d_out;

  u16* xw     = (u16*)d_ws;                                 // 18432*512
  u16* qkvT   = xw + (size_t)18432 * 512;                   // 1536*512
  u16* projT  = qkvT + (size_t)1536 * 512;                  // 512*512
  u16* qkvout = projT + (size_t)512 * 512;                  // 18432*1536
  u16* attno  = qkvout + (size_t)18432 * 1536;              // 18432*512

  prep_x_kernel<<<4608, 256, 0, stream>>>(x, xw);
  prep_wt_kernel<<<384, 256, 0, stream>>>(qkv_w, qkvT, 512, 1536);
  prep_wt_kernel<<<128, 256, 0, stream>>>(proj_w, projT, 512, 512);

  gemm_bt_kernel<0><<<dim3(144, 12), 256, 0, stream>>>(
      xw, qkvT, qkv_b, qkvout, nullptr, 18432, 1536, 512);

  attn_kernel<<<dim3(128, 16), 192, 0, stream>>>(qkvout, attno);

  gemm_bt_kernel<1><<<dim3(144, 4), 256, 0, stream>>>(
      attno, projT, proj_b, nullptr, out, 18432, 512, 512);
}

// Round 2
// 209.722 us; speedup vs baseline: 1.0817x; 1.0817x over previous
//
#include <hip/hip_runtime.h>
#include <hip/hip_bf16.h>

// Florence2VisionWindowAttention on MI355X (gfx950), bf16-MFMA pipeline.
// R1: + T2 XOR-swizzle on GEMM LDS (src-preswizzle + swizzled ds_read),
//     + attention per-mt P tiling (LDS 59KB -> 27KB, 5 blocks/CU).

typedef unsigned short u16;
typedef unsigned int u32;
typedef __attribute__((ext_vector_type(4))) float f32x4;
typedef __attribute__((ext_vector_type(8))) short short8;

#define MFMA16(a, b, c) __builtin_amdgcn_mfma_f32_16x16x32_bf16(a, b, c, 0, 0, 0)

__device__ __forceinline__ u16 f2b(float f) {
  __hip_bfloat16 h = __float2bfloat16(f);
  return *reinterpret_cast<u16*>(&h);
}

// ---------------- prep: gather x into window order + fp32->bf16 ----------------
__global__ void prep_x_kernel(const float* __restrict__ x, u16* __restrict__ xw) {
  int c = blockIdx.x * 256 + threadIdx.x;   // one 8-element chunk
  int r = c >> 6;                           // row in [0,18432): win*144+tok
  int colb = (c & 63) << 3;
  int win = r / 144, tok = r - win * 144;
  int b = win >> 4, wh = (win >> 2) & 3, ww = win & 3;
  int i = tok / 12, j = tok - i * 12;
  const float* src = x + ((size_t)((b * 48 + wh * 12 + i) * 48 + ww * 12 + j)) * 512 + colb;
  float4 a0 = *(const float4*)(src);
  float4 a1 = *(const float4*)(src + 4);
  short8 o;
  o[0] = (short)f2b(a0.x); o[1] = (short)f2b(a0.y); o[2] = (short)f2b(a0.z); o[3] = (short)f2b(a0.w);
  o[4] = (short)f2b(a1.x); o[5] = (short)f2b(a1.y); o[6] = (short)f2b(a1.z); o[7] = (short)f2b(a1.w);
  *reinterpret_cast<short8*>(xw + (size_t)r * 512 + colb) = o;
}

// ---------------- prep: weight transpose K x N -> N x K bf16 ----------------
__global__ void prep_wt_kernel(const float* __restrict__ w, u16* __restrict__ wt,
                               int K, int N) {
  int t = blockIdx.x * 256 + threadIdx.x;
  int nchunks = N >> 3;
  if (t >= K * nchunks) return;
  int k = t / nchunks;
  int n0 = (t - k * nchunks) << 3;
  const float* src = w + (size_t)k * N + n0;   // coalesced read
  float4 a0 = *(const float4*)(src);
  float4 a1 = *(const float4*)(src + 4);
  float v[8] = {a0.x, a0.y, a0.z, a0.w, a1.x, a1.y, a1.z, a1.w};
#pragma unroll
  for (int j = 0; j < 8; j++) wt[(size_t)(n0 + j) * K + k] = f2b(v[j]);
}

// ---------------- GEMM: C = A(MxK) * BT(NxK)^T + bias ----------------
// LDS tiles XOR-swizzled (16B slot ^= row&7) via pre-swizzled global source
// (global_load_lds writes linearly) + swizzled ds_read.
// EPI==0: bf16 output, row-major MxN.  EPI==1: fp32 output with window_reverse.
template <int EPI>
__global__ __launch_bounds__(256) void gemm_bt_kernel(
    const u16* __restrict__ A, const u16* __restrict__ BT,
    const float* __restrict__ bias,
    u16* __restrict__ outb, float* __restrict__ outf,
    int M, int N, int K) {
  __shared__ __align__(16) u16 sA[128 * 64];
  __shared__ __align__(16) u16 sB[128 * 64];
  const int tid = threadIdx.x;
  const int wave = tid >> 6;
  const int lane = tid & 63;
  const int bm = blockIdx.x;
  const int bn = blockIdx.y;
  const int wr = (wave >> 1) << 6;   // wave row offset in 128x128 tile
  const int wc = (wave & 1) << 6;    // wave col offset
  const int l15 = lane & 15;
  const int lhi = lane >> 4;

  f32x4 acc[4][4];
  const f32x4 fzero = {0.f, 0.f, 0.f, 0.f};
#pragma unroll
  for (int i = 0; i < 4; i++)
#pragma unroll
    for (int j = 0; j < 4; j++) acc[i][j] = fzero;

  const int srow = lane >> 3;                       // row within 8-row chunk (== row&7)
  const int scol = (((lane & 7) ^ srow) << 3);      // inverse-swizzled source column
  const u16* Abase = A + (size_t)(bm * 128) * K;
  const u16* Bbase = BT + (size_t)(bn * 128) * K;

  for (int k0 = 0; k0 < K; k0 += 64) {
#pragma unroll
    for (int i = 0; i < 4; ++i) {
      const int chunk = wave * 4 + i;          // wave-uniform
      const int row = chunk * 8 + srow;
      __builtin_amdgcn_global_load_lds(
          (const __attribute__((address_space(1))) u32*)(Abase + (size_t)row * K + k0 + scol),
          (__attribute__((address_space(3))) u32*)(sA + chunk * 512), 16, 0, 0);
      __builtin_amdgcn_global_load_lds(
          (const __attribute__((address_space(1))) u32*)(Bbase + (size_t)row * K + k0 + scol),
          (__attribute__((address_space(3))) u32*)(sB + chunk * 512), 16, 0, 0);
    }
    __syncthreads();

    short8 af[4][2], bfr[4][2];
#pragma unroll
    for (int t = 0; t < 4; t++) {
#pragma unroll
      for (int kk = 0; kk < 2; kk++) {
        const int rA = wr + t * 16 + l15;
        const int rB = wc + t * 16 + l15;
        const int cA = (kk * 32 + lhi * 8) ^ ((rA & 7) << 3);  // swizzled read col
        const int cB = (kk * 32 + lhi * 8) ^ ((rB & 7) << 3);
        af[t][kk]  = *reinterpret_cast<const short8*>(sA + rA * 64 + cA);
        bfr[t][kk] = *reinterpret_cast<const short8*>(sB + rB * 64 + cB);
      }
    }
#pragma unroll
    for (int kk = 0; kk < 2; kk++)
#pragma unroll
      for (int i = 0; i < 4; i++)
#pragma unroll
        for (int j = 0; j < 4; j++)
          acc[i][j] = MFMA16(af[i][kk], bfr[j][kk], acc[i][j]);
    __syncthreads();
  }

#pragma unroll
  for (int i = 0; i < 4; i++) {
    const int rowbase = bm * 128 + wr + i * 16 + lhi * 4;
#pragma unroll
    for (int j = 0; j < 4; j++) {
      const int col = bn * 128 + wc + j * 16 + l15;
      const float bv = bias[col];
#pragma unroll
      for (int r = 0; r < 4; r++) {
        float v = acc[i][j][r] + bv;
        int row = rowbase + r;
        if (EPI == 0) {
          outb[(size_t)row * N + col] = f2b(v);
        } else {
          int win = row / 144, tok = row - win * 144;
          int b = win >> 4, wh = (win >> 2) & 3, ww = win & 3;
          int ii = tok / 12, jj = tok - ii * 12;
          size_t o = ((size_t)b * 2304 + (wh * 12 + ii) * 48 + (ww * 12 + jj)) * 512 + col;
          outf[o] = v;
        }
      }
    }
  }
}

// ---------------- fused window attention: one block per (window, head) ----------------
// 192 threads = 3 waves, each wave owns 48 q-rows processed as 3 mt-tiles of 16.
// P buffered per-wave, 16 rows at a time (LDS total ~27KB -> 5 blocks/CU).
__global__ __launch_bounds__(192) void attn_kernel(const u16* __restrict__ qkv,
                                                   u16* __restrict__ outb) {
  constexpr int PSTR = 168;                         // row stride (336B: 16B-aligned, bank-spread)
  __shared__ __align__(16) u16 sVT[32 * PSTR];      // V^T (32 x 160 used)
  __shared__ __align__(16) u16 sP[3 * 16 * PSTR];   // per-wave 16-row P tile
  const int tid = threadIdx.x;
  const int wave = tid >> 6;
  const int lane = tid & 63;
  const int l15 = lane & 15;
  const int lhi = lane >> 4;
  const int win = blockIdx.x;
  const int head = blockIdx.y;
  const size_t base = ((size_t)win * 144) * 1536 + head * 32;
  const u16* Q = qkv + base;
  const u16* Kp = qkv + base + 512;
  const u16* V = qkv + base + 1024;
  constexpr float SC2 = 0.25509915922608635f;       // (1/sqrt(32)) * log2(e)
  const f32x4 fzero = {0.f, 0.f, 0.f, 0.f};

  // stage V^T into LDS (transpose): VT[d][tok]
  for (int t = tid; t < 576; t += 192) {
    int tok = t >> 2, dblk = t & 3;
    short8 v = *reinterpret_cast<const short8*>(V + (size_t)tok * 1536 + dblk * 8);
#pragma unroll
    for (int j = 0; j < 8; j++) sVT[(dblk * 8 + j) * PSTR + tok] = (u16)v[j];
  }
  for (int t = tid; t < 512; t += 192) {            // zero pad tok 144..159
    int d = t >> 4, cc = 144 + (t & 15);
    sVT[d * PSTR + cc] = 0;
  }
  u16* sPw = sP + wave * 16 * PSTR;
  {                                                 // zero own-wave P pad cols 144..159
    for (int t = lane; t < 256; t += 64) {
      int rr = t >> 4, cc = 144 + (t & 15);
      sPw[rr * PSTR + cc] = 0;
    }
  }

  // Q fragments (A-operand) and K fragments (B-operand) in registers
  short8 qa[3];
#pragma unroll
  for (int mt = 0; mt < 3; mt++) {
    int row = wave * 48 + mt * 16 + l15;
    qa[mt] = *reinterpret_cast<const short8*>(Q + (size_t)row * 1536 + lhi * 8);
  }
  short8 kb[9];
#pragma unroll
  for (int nt = 0; nt < 9; nt++) {
    int ctok = nt * 16 + l15;
    kb[nt] = *reinterpret_cast<const short8*>(Kp + (size_t)ctok * 1536 + lhi * 8);
  }

  __syncthreads();   // sVT ready for all waves

  f32x4 o[3][2];
#pragma unroll
  for (int mt = 0; mt < 3; mt++)
#pragma unroll
    for (int nt = 0; nt < 2; nt++) o[mt][nt] = fzero;

#pragma unroll
  for (int mt = 0; mt < 3; mt++) {
    // S = Q K^T for this 16-row tile: 9 tiles of 16x16 (K=32, one MFMA each)
    f32x4 s[9];
#pragma unroll
    for (int nt = 0; nt < 9; nt++) s[nt] = MFMA16(qa[mt], kb[nt], fzero);

    // softmax per row (row = lhi*4 + r; cols spread over 16-lane group x 9 tiles)
#pragma unroll
    for (int r = 0; r < 4; r++) {
      float m = -1e30f;
#pragma unroll
      for (int nt = 0; nt < 9; nt++) m = fmaxf(m, s[nt][r]);
#pragma unroll
      for (int off = 1; off < 16; off <<= 1) m = fmaxf(m, __shfl_xor(m, off, 64));
      float p[9], sum = 0.f;
#pragma unroll
      for (int nt = 0; nt < 9; nt++) {
        p[nt] = exp2f((s[nt][r] - m) * SC2);
        sum += p[nt];
      }
#pragma unroll
      for (int off = 1; off < 16; off <<= 1) sum += __shfl_xor(sum, off, 64);
      float inv = 1.f / sum;
      int prow = lhi * 4 + r;
#pragma unroll
      for (int nt = 0; nt < 9; nt++)
        sPw[prow * PSTR + nt * 16 + l15] = f2b(p[nt] * inv);
    }
    // (within-wave ds_write -> ds_read dependency: compiler inserts lgkmcnt)

    // O[mt] = P V : 2 col-tiles, K padded to 160 (5 MFMA steps)
#pragma unroll
    for (int kk = 0; kk < 5; kk++) {
      short8 pa = *reinterpret_cast<const short8*>(sPw + l15 * PSTR + kk * 32 + lhi * 8);
#pragma unroll
      for (int nt = 0; nt < 2; nt++) {
        short8 vb = *reinterpret_cast<const short8*>(sVT + (nt * 16 + l15) * PSTR + kk * 32 + lhi * 8);
        o[mt][nt] = MFMA16(pa, vb, o[mt][nt]);
      }
    }
  }

  // write O as bf16 into (M x 512) row-major (window-ordered rows)
  const int rowb = win * 144 + wave * 48;
#pragma unroll
  for (int mt = 0; mt < 3; mt++) {
#pragma unroll
    for (int nt = 0; nt < 2; nt++) {
      int col = head * 32 + nt * 16 + l15;
#pragma unroll
      for (int r = 0; r < 4; r++) {
        int row = rowb + mt * 16 + lhi * 4 + r;
        outb[(size_t)row * 512 + col] = f2b(o[mt][nt][r]);
      }
    }
  }
}

// ---------------- launch ----------------
extern "C" void kernel_launch(void* const* d_in, const int* in_sizes, int n_in,
                              void* d_out, int out_size, void* d_ws, size_t ws_size,
                              hipStream_t stream) {
  const float* x      = (const float*)d_in[0];
  const float* qkv_w  = (const float*)d_in[1];
  const float* qkv_b  = (const float*)d_in[2];
  const float* proj_w = (const float*)d_in[3];
  const float* proj_b = (const float*)d_in[4];
  float* out = (float*)d_out;

  u16* xw     = (u16*)d_ws;                                 // 18432*512
  u16* qkvT   = xw + (size_t)18432 * 512;                   // 1536*512
  u16* projT  = qkvT + (size_t)1536 * 512;                  // 512*512
  u16* qkvout = projT + (size_t)512 * 512;                  // 18432*1536
  u16* attno  = qkvout + (size_t)18432 * 1536;              // 18432*512

  prep_x_kernel<<<4608, 256, 0, stream>>>(x, xw);
  prep_wt_kernel<<<384, 256, 0, stream>>>(qkv_w, qkvT, 512, 1536);
  prep_wt_kernel<<<128, 256, 0, stream>>>(proj_w, projT, 512, 512);

  gemm_bt_kernel<0><<<dim3(144, 12), 256, 0, stream>>>(
      xw, qkvT, qkv_b, qkvout, nullptr, 18432, 1536, 512);

  attn_kernel<<<dim3(128, 16), 192, 0, stream>>>(qkvout, attno);

  gemm_bt_kernel<1><<<dim3(144, 4), 256, 0, stream>>>(
      attno, projT, proj_b, nullptr, out, 18432, 512, 512);
}